// Round 1
// baseline (221.795 us; speedup 1.0000x reference)
//
#include <hip/hip_runtime.h>
#include <math.h>

#define D 256
#define K2 512          // 2*D
#define N_NODES 100000
#define BATCH 1024      // n2
#define N1 11264        // n1 = B*(1+10)
#define S0 25
#define S1 10

// ---------------------------------------------------------------------------
// Kernel: transpose W (256 x 512, row-major) -> WT (512 x 256, row-major)
// LDS 64x65 tile, coalesced float4 reads and writes.
// ---------------------------------------------------------------------------
__global__ __launch_bounds__(256) void transpose_w(const float* __restrict__ W,
                                                   float* __restrict__ WT) {
    __shared__ float tile[64][65];
    const int j0 = blockIdx.x * 64;   // over D (256) -> 4 blocks
    const int k0 = blockIdx.y * 64;   // over K2 (512) -> 8 blocks
    const int t4 = threadIdx.x & 15;
    const int tr = threadIdx.x >> 4;  // 0..15
#pragma unroll
    for (int r = 0; r < 4; ++r) {
        int jj = r * 16 + tr;
        float4 v = *(const float4*)(W + (size_t)(j0 + jj) * K2 + k0 + t4 * 4);
        tile[jj][t4 * 4 + 0] = v.x;
        tile[jj][t4 * 4 + 1] = v.y;
        tile[jj][t4 * 4 + 2] = v.z;
        tile[jj][t4 * 4 + 3] = v.w;
    }
    __syncthreads();
#pragma unroll
    for (int r = 0; r < 4; ++r) {
        int kk = r * 16 + tr;
        float4 o;
        o.x = tile[t4 * 4 + 0][kk];
        o.y = tile[t4 * 4 + 1][kk];
        o.z = tile[t4 * 4 + 2][kk];
        o.w = tile[t4 * 4 + 3][kk];
        *(float4*)(WT + (size_t)(k0 + kk) * D + j0 + t4 * 4) = o;
    }
}

// ---------------------------------------------------------------------------
// Kernel: build X0[N1][512] = [ features[nodes1[i]] | mean_j features[neigh1[i][j]] ]
// One wave (64 lanes) per output node; lane l owns float4 at dims [4l,4l+4).
// ---------------------------------------------------------------------------
__global__ __launch_bounds__(256) void build_x0(const float* __restrict__ feat,
                                                const int* __restrict__ nodes2,
                                                const int* __restrict__ neigh2,
                                                const int* __restrict__ neigh1,
                                                float* __restrict__ X0) {
    const int wave = (blockIdx.x * blockDim.x + threadIdx.x) >> 6;
    const int lane = threadIdx.x & 63;
    if (wave >= N1) return;
    const int self_idx = (wave < BATCH) ? nodes2[wave] : neigh2[wave - BATCH];
    float4 selfv = ((const float4*)(feat + (size_t)self_idx * D))[lane];
    float4 acc = make_float4(0.f, 0.f, 0.f, 0.f);
    const int* nb = neigh1 + (size_t)wave * S0;
#pragma unroll
    for (int j = 0; j < S0; ++j) {
        int idx = nb[j];
        float4 v = ((const float4*)(feat + (size_t)idx * D))[lane];
        acc.x += v.x; acc.y += v.y; acc.z += v.z; acc.w += v.w;
    }
    const float s = 1.0f / (float)S0;
    acc.x *= s; acc.y *= s; acc.z *= s; acc.w *= s;
    float4* xrow = (float4*)(X0 + (size_t)wave * K2);
    xrow[lane] = selfv;       // dims [0,256)
    xrow[64 + lane] = acc;    // dims [256,512)
}

// ---------------------------------------------------------------------------
// Kernel: build X1[BATCH][512] = [ h1[i] | mean_j h1[1024 + i*10 + j] ]
// ---------------------------------------------------------------------------
__global__ __launch_bounds__(256) void build_x1(const float* __restrict__ h1,
                                                float* __restrict__ X1) {
    const int wave = (blockIdx.x * blockDim.x + threadIdx.x) >> 6;
    const int lane = threadIdx.x & 63;
    if (wave >= BATCH) return;
    float4 selfv = ((const float4*)(h1 + (size_t)wave * D))[lane];
    float4 acc = make_float4(0.f, 0.f, 0.f, 0.f);
#pragma unroll
    for (int j = 0; j < S1; ++j) {
        int row = BATCH + wave * S1 + j;
        float4 v = ((const float4*)(h1 + (size_t)row * D))[lane];
        acc.x += v.x; acc.y += v.y; acc.z += v.z; acc.w += v.w;
    }
    const float s = 1.0f / (float)S1;
    acc.x *= s; acc.y *= s; acc.z *= s; acc.w *= s;
    float4* xrow = (float4*)(X1 + (size_t)wave * K2);
    xrow[lane] = selfv;
    xrow[64 + lane] = acc;
}

// ---------------------------------------------------------------------------
// Kernel: Out[M][256] = l2norm_rows( relu( A[M][512] @ WT[512][256] + bias ) )
// BM rows per block, full 256-col width. 256 threads: tx=tid&15 (col group),
// ty=tid>>4 (row group, RPT rows each). Per-thread 16 cols at c = cc*64+tx*4+u.
// Row L2 norm reduced across the 16 tx lanes via shfl_xor.
// ---------------------------------------------------------------------------
template <int BM, int RPT>
__global__ __launch_bounds__(256) void gemm_relu_norm(const float* __restrict__ A,
                                                      const float* __restrict__ WT,
                                                      const float* __restrict__ bias,
                                                      float* __restrict__ Out) {
    constexpr int BK = 64;
    __shared__ float As[BM][BK + 4];   // stride 68 floats = 272B (16B aligned)
    __shared__ float Bs[BK][D];        // Bs[k][j] = WT[k0+k][j]
    const int tid = threadIdx.x;
    const int tx = tid & 15;
    const int ty = tid >> 4;
    const int row0 = blockIdx.x * BM;

    float acc[RPT][16];
#pragma unroll
    for (int r = 0; r < RPT; ++r)
#pragma unroll
        for (int c = 0; c < 16; ++c) acc[r][c] = 0.f;

    for (int k0 = 0; k0 < K2; k0 += BK) {
        // stage A tile: BM x 64
#pragma unroll
        for (int i = tid; i < BM * 16; i += 256) {
            int r = i >> 4, c4 = i & 15;
            float4 v = *(const float4*)(A + (size_t)(row0 + r) * K2 + k0 + c4 * 4);
            *(float4*)(&As[r][c4 * 4]) = v;
        }
        // stage B tile: 64 x 256, straight coalesced copy from WT
#pragma unroll
        for (int r = 0; r < 16; ++r) {
            int kr = (tid >> 6) + r * 4;
            int c4 = tid & 63;
            float4 v = *(const float4*)(WT + (size_t)(k0 + kr) * D + c4 * 4);
            *(float4*)(&Bs[kr][c4 * 4]) = v;
        }
        __syncthreads();
#pragma unroll 16
        for (int k = 0; k < BK; ++k) {
            float a[RPT];
#pragma unroll
            for (int r = 0; r < RPT; ++r) a[r] = As[ty * RPT + r][k];
#pragma unroll
            for (int cc = 0; cc < 4; ++cc) {
                float4 b = *(const float4*)(&Bs[k][cc * 64 + tx * 4]);
#pragma unroll
                for (int r = 0; r < RPT; ++r) {
                    acc[r][cc * 4 + 0] = fmaf(a[r], b.x, acc[r][cc * 4 + 0]);
                    acc[r][cc * 4 + 1] = fmaf(a[r], b.y, acc[r][cc * 4 + 1]);
                    acc[r][cc * 4 + 2] = fmaf(a[r], b.z, acc[r][cc * 4 + 2]);
                    acc[r][cc * 4 + 3] = fmaf(a[r], b.w, acc[r][cc * 4 + 3]);
                }
            }
        }
        __syncthreads();
    }

    // epilogue: bias + relu + row L2 normalize + store
#pragma unroll
    for (int r = 0; r < RPT; ++r) {
        const int row = row0 + ty * RPT + r;
        float ss = 0.f;
#pragma unroll
        for (int cc = 0; cc < 4; ++cc) {
#pragma unroll
            for (int u = 0; u < 4; ++u) {
                int c = cc * 64 + tx * 4 + u;
                float v = acc[r][cc * 4 + u] + bias[c];
                v = v > 0.f ? v : 0.f;
                acc[r][cc * 4 + u] = v;
                ss += v * v;
            }
        }
#pragma unroll
        for (int m = 1; m < 16; m <<= 1) ss += __shfl_xor(ss, m);
        const float inv = (ss > 0.f) ? (1.0f / sqrtf(ss)) : 1.0f;
#pragma unroll
        for (int cc = 0; cc < 4; ++cc) {
            float4 o;
            o.x = acc[r][cc * 4 + 0] * inv;
            o.y = acc[r][cc * 4 + 1] * inv;
            o.z = acc[r][cc * 4 + 2] * inv;
            o.w = acc[r][cc * 4 + 3] * inv;
            *(float4*)(Out + (size_t)row * D + cc * 64 + tx * 4) = o;
        }
    }
}

// ---------------------------------------------------------------------------
extern "C" void kernel_launch(void* const* d_in, const int* in_sizes, int n_in,
                              void* d_out, int out_size, void* d_ws, size_t ws_size,
                              hipStream_t stream) {
    const float* features = (const float*)d_in[0];
    const float* W0       = (const float*)d_in[1];
    const float* b0       = (const float*)d_in[2];
    const float* W1       = (const float*)d_in[3];
    const float* b1       = (const float*)d_in[4];
    const int*   nodes2   = (const int*)d_in[5];
    const int*   neigh2   = (const int*)d_in[6];
    const int*   neigh1   = (const int*)d_in[7];
    float* out = (float*)d_out;

    // workspace layout (floats)
    float* ws  = (float*)d_ws;
    float* WT0 = ws;                               // 512*256   = 131072
    float* WT1 = WT0 + 131072;                     // 131072
    float* X0  = WT1 + 131072;                     // 11264*512 = 5767168
    float* h1  = X0 + (size_t)N1 * K2;             // 11264*256 = 2883584
    float* X1  = h1 + (size_t)N1 * D;              // 1024*512  = 524288

    // 1. transpose weights
    transpose_w<<<dim3(4, 8), 256, 0, stream>>>(W0, WT0);
    transpose_w<<<dim3(4, 8), 256, 0, stream>>>(W1, WT1);

    // 2. gather + aggregate layer 0: X0 (11264 x 512)
    build_x0<<<N1 / 4, 256, 0, stream>>>(features, nodes2, neigh2, neigh1, X0);

    // 3. h1 = l2norm(relu(X0 @ W0^T + b0))  (11264 x 256)
    gemm_relu_norm<32, 2><<<N1 / 32, 256, 0, stream>>>(X0, WT0, b0, h1);

    // 4. X1 (1024 x 512)
    build_x1<<<BATCH / 4, 256, 0, stream>>>(h1, X1);

    // 5. out = l2norm(relu(X1 @ W1^T + b1))  (1024 x 256)
    gemm_relu_norm<16, 1><<<BATCH / 16, 256, 0, stream>>>(X1, WT1, b1, out);
}

// Round 2
// 125.010 us; speedup vs baseline: 1.7742x; 1.7742x over previous
//
#include <hip/hip_runtime.h>
#include <math.h>

#define D 256
#define K2 512          // 2*D
#define BATCH 1024      // n2
#define N1 11264        // n1 = B*(1+10)
#define S0 25
#define S1 10

typedef __bf16 bf16x8 __attribute__((ext_vector_type(8)));
typedef __bf16 bf16x4 __attribute__((ext_vector_type(4)));
typedef float  f32x4  __attribute__((ext_vector_type(4)));

// ---------------------------------------------------------------------------
// fp32 -> bf16 elementwise convert (for W0, W1)
// ---------------------------------------------------------------------------
__global__ __launch_bounds__(256) void f32_to_bf16(const float* __restrict__ in,
                                                   __bf16* __restrict__ out, int n4) {
    int i = blockIdx.x * blockDim.x + threadIdx.x;
    if (i >= n4) return;
    float4 v = ((const float4*)in)[i];
    bf16x4 o = { (__bf16)v.x, (__bf16)v.y, (__bf16)v.z, (__bf16)v.w };
    *(bf16x4*)(out + (size_t)i * 4) = o;
}

// ---------------------------------------------------------------------------
// build X0[N1][512] (bf16) = [ feat[nodes1[i]] | mean_j feat[neigh1[i][j]] ]
// One wave per output node; lane l owns dims [4l, 4l+4).
// ---------------------------------------------------------------------------
__global__ __launch_bounds__(256) void build_x0(const float* __restrict__ feat,
                                                const int* __restrict__ nodes2,
                                                const int* __restrict__ neigh2,
                                                const int* __restrict__ neigh1,
                                                __bf16* __restrict__ X0) {
    const int wave = (blockIdx.x * blockDim.x + threadIdx.x) >> 6;
    const int lane = threadIdx.x & 63;
    if (wave >= N1) return;
    const int self_idx = (wave < BATCH) ? nodes2[wave] : neigh2[wave - BATCH];
    float4 selfv = ((const float4*)(feat + (size_t)self_idx * D))[lane];
    float4 acc = make_float4(0.f, 0.f, 0.f, 0.f);
    const int* nb = neigh1 + (size_t)wave * S0;
#pragma unroll
    for (int j = 0; j < S0; ++j) {
        int idx = nb[j];
        float4 v = ((const float4*)(feat + (size_t)idx * D))[lane];
        acc.x += v.x; acc.y += v.y; acc.z += v.z; acc.w += v.w;
    }
    const float s = 1.0f / (float)S0;
    bf16x4 sv = { (__bf16)selfv.x, (__bf16)selfv.y, (__bf16)selfv.z, (__bf16)selfv.w };
    bf16x4 av = { (__bf16)(acc.x * s), (__bf16)(acc.y * s),
                  (__bf16)(acc.z * s), (__bf16)(acc.w * s) };
    __bf16* xrow = X0 + (size_t)wave * K2;
    *(bf16x4*)(xrow + lane * 4) = sv;         // dims [0,256)
    *(bf16x4*)(xrow + 256 + lane * 4) = av;   // dims [256,512)
}

// ---------------------------------------------------------------------------
// build X1[BATCH][512] (bf16) = [ h1[i] | mean_j h1[1024 + i*10 + j] ]  (h1 fp32)
// ---------------------------------------------------------------------------
__global__ __launch_bounds__(256) void build_x1(const float* __restrict__ h1,
                                                __bf16* __restrict__ X1) {
    const int wave = (blockIdx.x * blockDim.x + threadIdx.x) >> 6;
    const int lane = threadIdx.x & 63;
    if (wave >= BATCH) return;
    float4 selfv = ((const float4*)(h1 + (size_t)wave * D))[lane];
    float4 acc = make_float4(0.f, 0.f, 0.f, 0.f);
#pragma unroll
    for (int j = 0; j < S1; ++j) {
        int row = BATCH + wave * S1 + j;
        float4 v = ((const float4*)(h1 + (size_t)row * D))[lane];
        acc.x += v.x; acc.y += v.y; acc.z += v.z; acc.w += v.w;
    }
    const float s = 1.0f / (float)S1;
    bf16x4 sv = { (__bf16)selfv.x, (__bf16)selfv.y, (__bf16)selfv.z, (__bf16)selfv.w };
    bf16x4 av = { (__bf16)(acc.x * s), (__bf16)(acc.y * s),
                  (__bf16)(acc.z * s), (__bf16)(acc.w * s) };
    __bf16* xrow = X1 + (size_t)wave * K2;
    *(bf16x4*)(xrow + lane * 4) = sv;
    *(bf16x4*)(xrow + 256 + lane * 4) = av;
}

// ---------------------------------------------------------------------------
// MFMA GEMM: Out[M][256] = l2norm_rows(relu(A[M][512] @ W[256][512]^T + bias))
// A, W bf16 row-major; Out fp32. 256 threads = 4 waves; wave w owns cols
// [64w, 64w+64); block owns RB rows. 16x16x32 bf16 MFMA.
//
// LDS layout (16B blocks): tile16[group][kc][low] where group = row>>4 (A) or
// col>>4 (B), kc = k-chunk (8 bf16), low = row&15 / col&15. A wave's 8
// fragment reads per (kf) span a contiguous 1KB region -> conflict-free;
// staging writes are LDS-linear in tid -> conflict-free.
// Fragment mapping (m89-verified): A/B lane l: row/col = l&15, k = (l>>4)*8+i.
// C/D: col = l&15, row = (l>>4)*4 + reg.
// ---------------------------------------------------------------------------
template <int RB>
__global__ __launch_bounds__(256, 2) void gemm_bt_relu_norm(
        const __bf16* __restrict__ A, const __bf16* __restrict__ W,
        const float* __restrict__ bias, float* __restrict__ Out) {
    constexpr int RF = RB / 16;            // row fragments per wave
    constexpr int NA = RB * 8;             // 16B blocks in A tile (RB x 64)
    constexpr int ASTG = (NA + 255) / 256; // A staging iters
    __shared__ __bf16 As[RB * 64];
    __shared__ __bf16 Bs[256 * 64];
    __shared__ float ssLDS[4][RB];
    __shared__ float invLDS[RB];

    const int tid = threadIdx.x;
    const int row0 = blockIdx.x * RB;
    const int lane = tid & 63;
    const int w = tid >> 6;
    const int rl = lane & 15;
    const int g = lane >> 4;

    uint4 ra[ASTG], rb[8];

    // prologue: load k0 = 0 tile into regs
#pragma unroll
    for (int s = 0; s < ASTG; ++s) {
        int i = tid + s * 256;
        if (i < NA) {
            int rg = i >> 7, kc = (i >> 4) & 7, lo = i & 15;
            ra[s] = *(const uint4*)(A + (size_t)(row0 + rg * 16 + lo) * K2 + kc * 8);
        }
    }
#pragma unroll
    for (int s = 0; s < 8; ++s) {
        int i = tid + s * 256;
        int cg = i >> 7, kc = (i >> 4) & 7, lo = i & 15;
        rb[s] = *(const uint4*)(W + (size_t)(cg * 16 + lo) * K2 + kc * 8);
    }

    f32x4 acc[RF][4];
#pragma unroll
    for (int rf = 0; rf < RF; ++rf)
#pragma unroll
        for (int nf = 0; nf < 4; ++nf) acc[rf][nf] = (f32x4){0.f, 0.f, 0.f, 0.f};

    for (int k0 = 0; k0 < K2; k0 += 64) {
        // write staged regs to LDS (linear in tid)
#pragma unroll
        for (int s = 0; s < ASTG; ++s) {
            int i = tid + s * 256;
            if (i < NA) *(uint4*)(As + (size_t)i * 8) = ra[s];
        }
#pragma unroll
        for (int s = 0; s < 8; ++s) {
            int i = tid + s * 256;
            *(uint4*)(Bs + (size_t)i * 8) = rb[s];
        }
        __syncthreads();
        // prefetch next K tile into regs (hides L2 latency under MFMA)
        if (k0 + 64 < K2) {
            int kn = k0 + 64;
#pragma unroll
            for (int s = 0; s < ASTG; ++s) {
                int i = tid + s * 256;
                if (i < NA) {
                    int rg = i >> 7, kc = (i >> 4) & 7, lo = i & 15;
                    ra[s] = *(const uint4*)(A + (size_t)(row0 + rg * 16 + lo) * K2 + kn + kc * 8);
                }
            }
#pragma unroll
            for (int s = 0; s < 8; ++s) {
                int i = tid + s * 256;
                int cg = i >> 7, kc = (i >> 4) & 7, lo = i & 15;
                rb[s] = *(const uint4*)(W + (size_t)(cg * 16 + lo) * K2 + kn + kc * 8);
            }
        }
        // compute: 2 k-fragments per tile
#pragma unroll
        for (int kf = 0; kf < 2; ++kf) {
            const int kc = kf * 4 + g;
            bf16x8 af[RF], bf[4];
#pragma unroll
            for (int rf = 0; rf < RF; ++rf)
                af[rf] = *(const bf16x8*)(As + ((size_t)(rf * 8 + kc) * 16 + rl) * 8);
#pragma unroll
            for (int nf = 0; nf < 4; ++nf)
                bf[nf] = *(const bf16x8*)(Bs + ((size_t)((w * 4 + nf) * 8 + kc) * 16 + rl) * 8);
#pragma unroll
            for (int rf = 0; rf < RF; ++rf)
#pragma unroll
                for (int nf = 0; nf < 4; ++nf)
                    acc[rf][nf] = __builtin_amdgcn_mfma_f32_16x16x32_bf16(
                        af[rf], bf[nf], acc[rf][nf], 0, 0, 0);
        }
        __syncthreads();
    }

    // epilogue: bias + relu + row L2 norm (cross-wave via LDS) + store
    float bv[4];
#pragma unroll
    for (int nf = 0; nf < 4; ++nf) bv[nf] = bias[w * 64 + nf * 16 + rl];

#pragma unroll
    for (int rf = 0; rf < RF; ++rf) {
        float ss0 = 0.f, ss1 = 0.f, ss2 = 0.f, ss3 = 0.f;
#pragma unroll
        for (int nf = 0; nf < 4; ++nf) {
            float v0 = fmaxf(acc[rf][nf][0] + bv[nf], 0.f);
            float v1 = fmaxf(acc[rf][nf][1] + bv[nf], 0.f);
            float v2 = fmaxf(acc[rf][nf][2] + bv[nf], 0.f);
            float v3 = fmaxf(acc[rf][nf][3] + bv[nf], 0.f);
            acc[rf][nf][0] = v0; acc[rf][nf][1] = v1;
            acc[rf][nf][2] = v2; acc[rf][nf][3] = v3;
            ss0 += v0 * v0; ss1 += v1 * v1; ss2 += v2 * v2; ss3 += v3 * v3;
        }
#pragma unroll
        for (int m = 1; m < 16; m <<= 1) {
            ss0 += __shfl_xor(ss0, m);
            ss1 += __shfl_xor(ss1, m);
            ss2 += __shfl_xor(ss2, m);
            ss3 += __shfl_xor(ss3, m);
        }
        float ssv = (rl == 0) ? ss0 : (rl == 1) ? ss1 : (rl == 2) ? ss2 : ss3;
        if (rl < 4) ssLDS[w][rf * 16 + g * 4 + rl] = ssv;
    }
    __syncthreads();
    if (tid < RB) {
        float t = ssLDS[0][tid] + ssLDS[1][tid] + ssLDS[2][tid] + ssLDS[3][tid];
        invLDS[tid] = (t > 0.f) ? rsqrtf(t) : 1.0f;
    }
    __syncthreads();
#pragma unroll
    for (int rf = 0; rf < RF; ++rf)
#pragma unroll
        for (int j = 0; j < 4; ++j) {
            const int row = rf * 16 + g * 4 + j;
            const float inv = invLDS[row];
#pragma unroll
            for (int nf = 0; nf < 4; ++nf)
                Out[(size_t)(row0 + row) * D + w * 64 + nf * 16 + rl] = acc[rf][nf][j] * inv;
        }
}

// ---------------------------------------------------------------------------
extern "C" void kernel_launch(void* const* d_in, const int* in_sizes, int n_in,
                              void* d_out, int out_size, void* d_ws, size_t ws_size,
                              hipStream_t stream) {
    const float* features = (const float*)d_in[0];
    const float* W0       = (const float*)d_in[1];
    const float* b0       = (const float*)d_in[2];
    const float* W1       = (const float*)d_in[3];
    const float* b1       = (const float*)d_in[4];
    const int*   nodes2   = (const int*)d_in[5];
    const int*   neigh2   = (const int*)d_in[6];
    const int*   neigh1   = (const int*)d_in[7];
    float* out = (float*)d_out;

    // workspace layout
    char* ws = (char*)d_ws;
    __bf16* Wb0 = (__bf16*)ws;                              // 256*512*2 = 256 KB
    __bf16* Wb1 = (__bf16*)(ws + 262144);                   // 256 KB
    __bf16* X0b = (__bf16*)(ws + 524288);                   // 11264*512*2 = 11.5 MB
    float*  h1  = (float*)(ws + 524288 + 11534336);         // 11264*256*4 = 11.5 MB
    __bf16* X1b = (__bf16*)(ws + 524288 + 2 * 11534336);    // 1024*512*2 = 1 MB

    // 1. convert weights to bf16 (no transpose needed: W is already B^T layout)
    f32_to_bf16<<<128, 256, 0, stream>>>(W0, Wb0, 32768);
    f32_to_bf16<<<128, 256, 0, stream>>>(W1, Wb1, 32768);

    // 2. gather + aggregate layer 0: X0b (11264 x 512 bf16)
    build_x0<<<N1 / 4, 256, 0, stream>>>(features, nodes2, neigh2, neigh1, X0b);

    // 3. h1 = l2norm(relu(X0b @ W0^T + b0))  (11264 x 256 fp32)
    gemm_bt_relu_norm<64><<<N1 / 64, 256, 0, stream>>>(X0b, Wb0, b0, h1);

    // 4. X1b (1024 x 512 bf16)
    build_x1<<<BATCH / 4, 256, 0, stream>>>(h1, X1b);

    // 5. out = l2norm(relu(X1b @ W1^T + b1))  (1024 x 256 fp32)
    gemm_bt_relu_norm<16><<<BATCH / 16, 256, 0, stream>>>(X1b, Wb1, b1, out);
}

// Round 3
// 114.817 us; speedup vs baseline: 1.9317x; 1.0888x over previous
//
#include <hip/hip_runtime.h>
#include <math.h>

#define D 256
#define K2 512          // 2*D
#define BATCH 1024      // n2
#define N1 11264        // n1 = B*(1+10)
#define S0 25
#define S1 10

typedef __bf16 bf16x8 __attribute__((ext_vector_type(8)));
typedef __bf16 bf16x4 __attribute__((ext_vector_type(4)));
typedef float  f32x4  __attribute__((ext_vector_type(4)));

// ---------------------------------------------------------------------------
// Kernel A: convert W0/W1 to bf16 (first 65536 threads) + build
// X0[N1][512] (bf16) = [ feat[nodes1[i]] | mean_j feat[neigh1[i][j]] ].
// One wave per output node; lane l owns dims [4l, 4l+4).
// ---------------------------------------------------------------------------
__global__ __launch_bounds__(256) void prep_kernel(
        const float* __restrict__ feat, const float* __restrict__ W0,
        const float* __restrict__ W1, const int* __restrict__ nodes2,
        const int* __restrict__ neigh2, const int* __restrict__ neigh1,
        __bf16* __restrict__ Wb0, __bf16* __restrict__ Wb1,
        __bf16* __restrict__ X0) {
    const int gtid = blockIdx.x * 256 + threadIdx.x;
    // weight convert: 32768 float4 per W
    if (gtid < 65536) {
        const float* src = (gtid < 32768) ? W0 : W1;
        __bf16* dst = (gtid < 32768) ? Wb0 : Wb1;
        const int i = gtid & 32767;
        float4 v = ((const float4*)src)[i];
        bf16x4 o = { (__bf16)v.x, (__bf16)v.y, (__bf16)v.z, (__bf16)v.w };
        *(bf16x4*)(dst + (size_t)i * 4) = o;
    }
    const int wave = gtid >> 6;
    const int lane = threadIdx.x & 63;
    if (wave >= N1) return;
    const int self_idx = (wave < BATCH) ? nodes2[wave] : neigh2[wave - BATCH];
    float4 selfv = ((const float4*)(feat + (size_t)self_idx * D))[lane];
    float4 acc = make_float4(0.f, 0.f, 0.f, 0.f);
    const int* nb = neigh1 + (size_t)wave * S0;
#pragma unroll
    for (int j = 0; j < S0; ++j) {
        int idx = nb[j];
        float4 v = ((const float4*)(feat + (size_t)idx * D))[lane];
        acc.x += v.x; acc.y += v.y; acc.z += v.z; acc.w += v.w;
    }
    const float s = 1.0f / (float)S0;
    bf16x4 sv = { (__bf16)selfv.x, (__bf16)selfv.y, (__bf16)selfv.z, (__bf16)selfv.w };
    bf16x4 av = { (__bf16)(acc.x * s), (__bf16)(acc.y * s),
                  (__bf16)(acc.z * s), (__bf16)(acc.w * s) };
    __bf16* xrow = X0 + (size_t)wave * K2;
    *(bf16x4*)(xrow + lane * 4) = sv;         // dims [0,256)
    *(bf16x4*)(xrow + 256 + lane * 4) = av;   // dims [256,512)
}

// ---------------------------------------------------------------------------
// MFMA GEMM: Out[M][256] = l2norm_rows(relu(A[M][512] @ W[256][512]^T + bias))
// A, W bf16 row-major; Out templated (bf16 for layer 0, fp32 for layer 1).
// 256 threads = 4 waves; wave w owns cols [64w, 64w+64); block owns RB rows.
// LDS tile16 layout: slot i -> group i>>7, k-chunk (i>>4)&7, low i&15; a
// wave's fragment reads per kf span contiguous 1KB -> conflict-free (m136);
// staging writes LDS-linear in tid -> conflict-free.
// Fragment mapping (m89): A/B lane l: row/col=l&15, k=(l>>4)*8+i.
// C/D: col=l&15, row=(l>>4)*4+reg.
// ---------------------------------------------------------------------------
template <int RB, typename OutT>
__global__ __launch_bounds__(256, 2) void gemm_bt_relu_norm(
        const __bf16* __restrict__ A, const __bf16* __restrict__ W,
        const float* __restrict__ bias, OutT* __restrict__ Out) {
    constexpr int RF = RB / 16;            // row fragments per wave
    constexpr int NA = RB * 8;             // 16B blocks in A tile (RB x 64)
    constexpr int ASTG = (NA + 255) / 256;
    __shared__ __bf16 As[RB * 64];
    __shared__ __bf16 Bs[256 * 64];
    __shared__ float ssLDS[4][RB];
    __shared__ float invLDS[RB];

    const int tid = threadIdx.x;
    const int row0 = blockIdx.x * RB;
    const int lane = tid & 63;
    const int w = tid >> 6;
    const int rl = lane & 15;
    const int g = lane >> 4;

    uint4 ra[ASTG], rb[8];

#pragma unroll
    for (int s = 0; s < ASTG; ++s) {
        int i = tid + s * 256;
        if (i < NA) {
            int rg = i >> 7, kc = (i >> 4) & 7, lo = i & 15;
            ra[s] = *(const uint4*)(A + (size_t)(row0 + rg * 16 + lo) * K2 + kc * 8);
        }
    }
#pragma unroll
    for (int s = 0; s < 8; ++s) {
        int i = tid + s * 256;
        int cg = i >> 7, kc = (i >> 4) & 7, lo = i & 15;
        rb[s] = *(const uint4*)(W + (size_t)(cg * 16 + lo) * K2 + kc * 8);
    }

    f32x4 acc[RF][4];
#pragma unroll
    for (int rf = 0; rf < RF; ++rf)
#pragma unroll
        for (int nf = 0; nf < 4; ++nf) acc[rf][nf] = (f32x4){0.f, 0.f, 0.f, 0.f};

    for (int k0 = 0; k0 < K2; k0 += 64) {
#pragma unroll
        for (int s = 0; s < ASTG; ++s) {
            int i = tid + s * 256;
            if (i < NA) *(uint4*)(As + (size_t)i * 8) = ra[s];
        }
#pragma unroll
        for (int s = 0; s < 8; ++s) {
            int i = tid + s * 256;
            *(uint4*)(Bs + (size_t)i * 8) = rb[s];
        }
        __syncthreads();
        if (k0 + 64 < K2) {
            int kn = k0 + 64;
#pragma unroll
            for (int s = 0; s < ASTG; ++s) {
                int i = tid + s * 256;
                if (i < NA) {
                    int rg = i >> 7, kc = (i >> 4) & 7, lo = i & 15;
                    ra[s] = *(const uint4*)(A + (size_t)(row0 + rg * 16 + lo) * K2 + kn + kc * 8);
                }
            }
#pragma unroll
            for (int s = 0; s < 8; ++s) {
                int i = tid + s * 256;
                int cg = i >> 7, kc = (i >> 4) & 7, lo = i & 15;
                rb[s] = *(const uint4*)(W + (size_t)(cg * 16 + lo) * K2 + kn + kc * 8);
            }
        }
#pragma unroll
        for (int kf = 0; kf < 2; ++kf) {
            const int kc = kf * 4 + g;
            bf16x8 af[RF], bfr[4];
#pragma unroll
            for (int rf = 0; rf < RF; ++rf)
                af[rf] = *(const bf16x8*)(As + ((size_t)(rf * 8 + kc) * 16 + rl) * 8);
#pragma unroll
            for (int nf = 0; nf < 4; ++nf)
                bfr[nf] = *(const bf16x8*)(Bs + ((size_t)((w * 4 + nf) * 8 + kc) * 16 + rl) * 8);
#pragma unroll
            for (int rf = 0; rf < RF; ++rf)
#pragma unroll
                for (int nf = 0; nf < 4; ++nf)
                    acc[rf][nf] = __builtin_amdgcn_mfma_f32_16x16x32_bf16(
                        af[rf], bfr[nf], acc[rf][nf], 0, 0, 0);
        }
        __syncthreads();
    }

    float bv[4];
#pragma unroll
    for (int nf = 0; nf < 4; ++nf) bv[nf] = bias[w * 64 + nf * 16 + rl];

#pragma unroll
    for (int rf = 0; rf < RF; ++rf) {
        float ss0 = 0.f, ss1 = 0.f, ss2 = 0.f, ss3 = 0.f;
#pragma unroll
        for (int nf = 0; nf < 4; ++nf) {
            float v0 = fmaxf(acc[rf][nf][0] + bv[nf], 0.f);
            float v1 = fmaxf(acc[rf][nf][1] + bv[nf], 0.f);
            float v2 = fmaxf(acc[rf][nf][2] + bv[nf], 0.f);
            float v3 = fmaxf(acc[rf][nf][3] + bv[nf], 0.f);
            acc[rf][nf][0] = v0; acc[rf][nf][1] = v1;
            acc[rf][nf][2] = v2; acc[rf][nf][3] = v3;
            ss0 += v0 * v0; ss1 += v1 * v1; ss2 += v2 * v2; ss3 += v3 * v3;
        }
#pragma unroll
        for (int m = 1; m < 16; m <<= 1) {
            ss0 += __shfl_xor(ss0, m);
            ss1 += __shfl_xor(ss1, m);
            ss2 += __shfl_xor(ss2, m);
            ss3 += __shfl_xor(ss3, m);
        }
        float ssv = (rl == 0) ? ss0 : (rl == 1) ? ss1 : (rl == 2) ? ss2 : ss3;
        if (rl < 4) ssLDS[w][rf * 16 + g * 4 + rl] = ssv;
    }
    __syncthreads();
    if (tid < RB) {
        float t = ssLDS[0][tid] + ssLDS[1][tid] + ssLDS[2][tid] + ssLDS[3][tid];
        invLDS[tid] = (t > 0.f) ? rsqrtf(t) : 1.0f;
    }
    __syncthreads();
#pragma unroll
    for (int rf = 0; rf < RF; ++rf)
#pragma unroll
        for (int j = 0; j < 4; ++j) {
            const int row = rf * 16 + g * 4 + j;
            const float inv = invLDS[row];
#pragma unroll
            for (int nf = 0; nf < 4; ++nf)
                Out[(size_t)(row0 + row) * D + w * 64 + nf * 16 + rl] =
                    (OutT)(acc[rf][nf][j] * inv);
        }
}

// ---------------------------------------------------------------------------
// Kernel C: layer-1 GEMM with FUSED aggregation staging.
// Out[1024][256] = l2norm(relu(X1 @ W1^T + b1)) where X1 row i =
// [ h1[i] | mean_j h1[1024+i*10+j] ], h1 bf16, built on the fly in A-staging.
// RB=32 rows/block, same tile16 LDS layout and wave mapping as above.
// ---------------------------------------------------------------------------
__global__ __launch_bounds__(256, 2) void gemm1_fused(
        const __bf16* __restrict__ h1, const __bf16* __restrict__ W,
        const float* __restrict__ bias, float* __restrict__ Out) {
    constexpr int RB = 32;
    __shared__ __bf16 As[RB * 64];
    __shared__ __bf16 Bs[256 * 64];
    __shared__ float ssLDS[4][RB];
    __shared__ float invLDS[RB];

    const int tid = threadIdx.x;
    const int row0 = blockIdx.x * RB;
    const int lane = tid & 63;
    const int w = tid >> 6;
    const int rl = lane & 15;
    const int g = lane >> 4;
    // this thread's A slot: row rg*16+lo, k-chunk kc (8 bf16)
    const int rg = tid >> 7, kc8 = (tid >> 4) & 7, lo = tid & 15;
    const int grow = row0 + rg * 16 + lo;

    f32x4 acc[2][4];
#pragma unroll
    for (int rf = 0; rf < 2; ++rf)
#pragma unroll
        for (int nf = 0; nf < 4; ++nf) acc[rf][nf] = (f32x4){0.f, 0.f, 0.f, 0.f};

    for (int k0 = 0; k0 < K2; k0 += 64) {
        // --- fused A-staging (build X1 tile on the fly) ---
        bf16x8 av;
        if (k0 < 256) {
            av = *(const bf16x8*)(h1 + (size_t)grow * D + k0 + kc8 * 8);
        } else {
            float f[8];
#pragma unroll
            for (int e = 0; e < 8; ++e) f[e] = 0.f;
            const __bf16* base = h1 + (size_t)(BATCH + grow * S1) * D + (k0 - 256) + kc8 * 8;
#pragma unroll
            for (int j = 0; j < S1; ++j) {
                bf16x8 v = *(const bf16x8*)(base + (size_t)j * D);
#pragma unroll
                for (int e = 0; e < 8; ++e) f[e] += (float)v[e];
            }
#pragma unroll
            for (int e = 0; e < 8; ++e) av[e] = (__bf16)(f[e] * 0.1f);
        }
        *(bf16x8*)(As + (size_t)tid * 8) = av;
        // --- B-staging ---
#pragma unroll
        for (int s = 0; s < 8; ++s) {
            int i = tid + s * 256;
            int cg = i >> 7, kc = (i >> 4) & 7, blo = i & 15;
            *(uint4*)(Bs + (size_t)i * 8) =
                *(const uint4*)(W + (size_t)(cg * 16 + blo) * K2 + k0 + kc * 8);
        }
        __syncthreads();
#pragma unroll
        for (int kf = 0; kf < 2; ++kf) {
            const int kc = kf * 4 + g;
            bf16x8 af[2], bfr[4];
#pragma unroll
            for (int rf = 0; rf < 2; ++rf)
                af[rf] = *(const bf16x8*)(As + ((size_t)(rf * 8 + kc) * 16 + rl) * 8);
#pragma unroll
            for (int nf = 0; nf < 4; ++nf)
                bfr[nf] = *(const bf16x8*)(Bs + ((size_t)((w * 4 + nf) * 8 + kc) * 16 + rl) * 8);
#pragma unroll
            for (int rf = 0; rf < 2; ++rf)
#pragma unroll
                for (int nf = 0; nf < 4; ++nf)
                    acc[rf][nf] = __builtin_amdgcn_mfma_f32_16x16x32_bf16(
                        af[rf], bfr[nf], acc[rf][nf], 0, 0, 0);
        }
        __syncthreads();
    }

    float bv[4];
#pragma unroll
    for (int nf = 0; nf < 4; ++nf) bv[nf] = bias[w * 64 + nf * 16 + rl];

#pragma unroll
    for (int rf = 0; rf < 2; ++rf) {
        float ss0 = 0.f, ss1 = 0.f, ss2 = 0.f, ss3 = 0.f;
#pragma unroll
        for (int nf = 0; nf < 4; ++nf) {
            float v0 = fmaxf(acc[rf][nf][0] + bv[nf], 0.f);
            float v1 = fmaxf(acc[rf][nf][1] + bv[nf], 0.f);
            float v2 = fmaxf(acc[rf][nf][2] + bv[nf], 0.f);
            float v3 = fmaxf(acc[rf][nf][3] + bv[nf], 0.f);
            acc[rf][nf][0] = v0; acc[rf][nf][1] = v1;
            acc[rf][nf][2] = v2; acc[rf][nf][3] = v3;
            ss0 += v0 * v0; ss1 += v1 * v1; ss2 += v2 * v2; ss3 += v3 * v3;
        }
#pragma unroll
        for (int m = 1; m < 16; m <<= 1) {
            ss0 += __shfl_xor(ss0, m);
            ss1 += __shfl_xor(ss1, m);
            ss2 += __shfl_xor(ss2, m);
            ss3 += __shfl_xor(ss3, m);
        }
        float ssv = (rl == 0) ? ss0 : (rl == 1) ? ss1 : (rl == 2) ? ss2 : ss3;
        if (rl < 4) ssLDS[w][rf * 16 + g * 4 + rl] = ssv;
    }
    __syncthreads();
    if (tid < RB) {
        float t = ssLDS[0][tid] + ssLDS[1][tid] + ssLDS[2][tid] + ssLDS[3][tid];
        invLDS[tid] = (t > 0.f) ? rsqrtf(t) : 1.0f;
    }
    __syncthreads();
#pragma unroll
    for (int rf = 0; rf < 2; ++rf)
#pragma unroll
        for (int j = 0; j < 4; ++j) {
            const int row = rf * 16 + g * 4 + j;
            const float inv = invLDS[row];
#pragma unroll
            for (int nf = 0; nf < 4; ++nf)
                Out[(size_t)(row0 + row) * D + w * 64 + nf * 16 + rl] = acc[rf][nf][j] * inv;
        }
}

// ---------------------------------------------------------------------------
extern "C" void kernel_launch(void* const* d_in, const int* in_sizes, int n_in,
                              void* d_out, int out_size, void* d_ws, size_t ws_size,
                              hipStream_t stream) {
    const float* features = (const float*)d_in[0];
    const float* W0       = (const float*)d_in[1];
    const float* b0       = (const float*)d_in[2];
    const float* W1       = (const float*)d_in[3];
    const float* b1       = (const float*)d_in[4];
    const int*   nodes2   = (const int*)d_in[5];
    const int*   neigh2   = (const int*)d_in[6];
    const int*   neigh1   = (const int*)d_in[7];
    float* out = (float*)d_out;

    // workspace layout
    char* ws = (char*)d_ws;
    __bf16* Wb0 = (__bf16*)ws;                        // 256 KB
    __bf16* Wb1 = (__bf16*)(ws + 262144);             // 256 KB
    __bf16* X0b = (__bf16*)(ws + 524288);             // 11264*512*2 = 11.5 MB
    __bf16* h1b = (__bf16*)(ws + 524288 + 11534336);  // 11264*256*2 = 5.75 MB

    // A: convert weights + gather/aggregate layer 0
    prep_kernel<<<N1 / 4, 256, 0, stream>>>(features, W0, W1, nodes2, neigh2,
                                            neigh1, Wb0, Wb1, X0b);

    // B: h1 (bf16) = l2norm(relu(X0b @ W0^T + b0))
    gemm_bt_relu_norm<32, __bf16><<<N1 / 32, 256, 0, stream>>>(X0b, Wb0, b0, h1b);

    // C: out = l2norm(relu([h1|agg(h1)] @ W1^T + b1)), aggregation fused
    gemm1_fused<<<BATCH / 32, 256, 0, stream>>>(h1b, Wb1, b1, out);
}

// Round 4
// 101.230 us; speedup vs baseline: 2.1910x; 1.1342x over previous
//
#include <hip/hip_runtime.h>
#include <math.h>

#define D 256
#define K2 512          // 2*D
#define BATCH 1024      // n2
#define N1 11264        // n1 = B*(1+10)
#define S0 25
#define S1 10

typedef __bf16 bf16x8 __attribute__((ext_vector_type(8)));
typedef __bf16 bf16x4 __attribute__((ext_vector_type(4)));
typedef float  f32x4  __attribute__((ext_vector_type(4)));

// ---------------------------------------------------------------------------
// fused_layer0: per block of 32 output rows:
//   phase 1 (gather): wave w gathers rows [8w, 8w+8): self row + mean of 25
//     neighbor rows from features (fp32), converts to bf16, writes a full-K
//     LDS A-tile [32][512] with XOR granule swizzle (granule ^= row&7) so the
//     MFMA fragment ds_read_b128 (16 lanes at row-stride 1KB) is conflict-free.
//   phase 2 (GEMM): 8 k-tiles of 64; B staged from fp32 W0 with inline bf16
//     convert (reg-prefetched); 16x16x32 bf16 MFMA; A never re-staged.
//   epilogue: bias + relu + row-l2norm -> h1b (bf16).
// Fragment mapping (m89): A/B lane l: row/col=l&15, k=(l>>4)*8+i.
// C/D: col=l&15, row=(l>>4)*4+reg.
// ---------------------------------------------------------------------------
__global__ __launch_bounds__(256, 2) void fused_layer0(
        const float* __restrict__ feat, const float* __restrict__ W0,
        const float* __restrict__ b0, const int* __restrict__ nodes2,
        const int* __restrict__ neigh2, const int* __restrict__ neigh1,
        __bf16* __restrict__ h1b) {
    __shared__ __bf16 Atile[32 * 512];   // 32KB, swizzled granules of 8 bf16
    __shared__ __bf16 Bs[256 * 64];      // 32KB, tile16 layout
    __shared__ float ssLDS[4][32];
    __shared__ float invLDS[32];

    const int tid = threadIdx.x;
    const int lane = tid & 63;
    const int w = tid >> 6;
    const int rl = lane & 15;
    const int g = lane >> 4;
    const int row0 = blockIdx.x * 32;

    // ---- B prologue loads (k0 = 0), fp32, 2 float4 per slot ----
    float4 rb0[8], rb1[8];
#pragma unroll
    for (int s = 0; s < 8; ++s) {
        int i = tid + s * 256;
        int cg = i >> 7, kc = (i >> 4) & 7, lo = i & 15;
        const float* p = W0 + (size_t)(cg * 16 + lo) * K2 + kc * 8;
        rb0[s] = *(const float4*)p;
        rb1[s] = *(const float4*)(p + 4);
    }

    // ---- gather phase: wave w handles rows [8w, 8w+8) ----
#pragma unroll 1
    for (int r = w * 8; r < w * 8 + 8; ++r) {
        const int gr = row0 + r;
        const int self_idx = (gr < BATCH) ? nodes2[gr] : neigh2[gr - BATCH];
        const int* nb = neigh1 + (size_t)gr * S0;
        float4 sv = ((const float4*)(feat + (size_t)self_idx * D))[lane];
        float4 v[13];
        float4 acc = make_float4(0.f, 0.f, 0.f, 0.f);
#pragma unroll
        for (int j = 0; j < 13; ++j)
            v[j] = ((const float4*)(feat + (size_t)nb[j] * D))[lane];
#pragma unroll
        for (int j = 0; j < 13; ++j) {
            acc.x += v[j].x; acc.y += v[j].y; acc.z += v[j].z; acc.w += v[j].w;
        }
#pragma unroll
        for (int j = 0; j < 12; ++j)
            v[j] = ((const float4*)(feat + (size_t)nb[13 + j] * D))[lane];
#pragma unroll
        for (int j = 0; j < 12; ++j) {
            acc.x += v[j].x; acc.y += v[j].y; acc.z += v[j].z; acc.w += v[j].w;
        }
        const float s25 = 1.0f / 25.0f;
        bf16x4 svb = { (__bf16)sv.x, (__bf16)sv.y, (__bf16)sv.z, (__bf16)sv.w };
        bf16x4 avb = { (__bf16)(acc.x * s25), (__bf16)(acc.y * s25),
                       (__bf16)(acc.z * s25), (__bf16)(acc.w * s25) };
        // self dims [4l,4l+4) -> granule l>>1 (half l&1); agg dims +256 -> +32 granules
        const int sw = r & 7;
        const int gs = (lane >> 1) ^ sw;
        const int ga = (32 + (lane >> 1)) ^ sw;
        *(bf16x4*)(Atile + (size_t)r * 512 + gs * 8 + (lane & 1) * 4) = svb;
        *(bf16x4*)(Atile + (size_t)r * 512 + ga * 8 + (lane & 1) * 4) = avb;
    }
    __syncthreads();

    // ---- GEMM phase ----
    f32x4 acc[2][4];
#pragma unroll
    for (int rf = 0; rf < 2; ++rf)
#pragma unroll
        for (int nf = 0; nf < 4; ++nf) acc[rf][nf] = (f32x4){0.f, 0.f, 0.f, 0.f};

    for (int k0 = 0; k0 < K2; k0 += 64) {
        // write Bs from prefetched fp32 regs with inline cvt (linear in tid)
#pragma unroll
        for (int s = 0; s < 8; ++s) {
            int i = tid + s * 256;
            bf16x8 bv;
            bv[0] = (__bf16)rb0[s].x; bv[1] = (__bf16)rb0[s].y;
            bv[2] = (__bf16)rb0[s].z; bv[3] = (__bf16)rb0[s].w;
            bv[4] = (__bf16)rb1[s].x; bv[5] = (__bf16)rb1[s].y;
            bv[6] = (__bf16)rb1[s].z; bv[7] = (__bf16)rb1[s].w;
            *(bf16x8*)(Bs + (size_t)i * 8) = bv;
        }
        __syncthreads();
        if (k0 + 64 < K2) {
#pragma unroll
            for (int s = 0; s < 8; ++s) {
                int i = tid + s * 256;
                int cg = i >> 7, kc = (i >> 4) & 7, lo = i & 15;
                const float* p = W0 + (size_t)(cg * 16 + lo) * K2 + (k0 + 64) + kc * 8;
                rb0[s] = *(const float4*)p;
                rb1[s] = *(const float4*)(p + 4);
            }
        }
#pragma unroll
        for (int kf = 0; kf < 2; ++kf) {
            const int kc = kf * 4 + g;
            const int gA = (k0 >> 3) + kc;  // granule index within a row
            bf16x8 af[2], bfr[4];
#pragma unroll
            for (int rf = 0; rf < 2; ++rf) {
                int row = rf * 16 + rl;
                af[rf] = *(const bf16x8*)(Atile + (size_t)row * 512 +
                                          (size_t)(gA ^ (row & 7)) * 8);
            }
#pragma unroll
            for (int nf = 0; nf < 4; ++nf)
                bfr[nf] = *(const bf16x8*)(Bs + ((size_t)((w * 4 + nf) * 8 + kc) * 16 + rl) * 8);
#pragma unroll
            for (int rf = 0; rf < 2; ++rf)
#pragma unroll
                for (int nf = 0; nf < 4; ++nf)
                    acc[rf][nf] = __builtin_amdgcn_mfma_f32_16x16x32_bf16(
                        af[rf], bfr[nf], acc[rf][nf], 0, 0, 0);
        }
        __syncthreads();
    }

    // ---- epilogue: bias + relu + row L2 norm + store bf16 ----
    float bv[4];
#pragma unroll
    for (int nf = 0; nf < 4; ++nf) bv[nf] = b0[w * 64 + nf * 16 + rl];

#pragma unroll
    for (int rf = 0; rf < 2; ++rf) {
        float ss0 = 0.f, ss1 = 0.f, ss2 = 0.f, ss3 = 0.f;
#pragma unroll
        for (int nf = 0; nf < 4; ++nf) {
            float v0 = fmaxf(acc[rf][nf][0] + bv[nf], 0.f);
            float v1 = fmaxf(acc[rf][nf][1] + bv[nf], 0.f);
            float v2 = fmaxf(acc[rf][nf][2] + bv[nf], 0.f);
            float v3 = fmaxf(acc[rf][nf][3] + bv[nf], 0.f);
            acc[rf][nf][0] = v0; acc[rf][nf][1] = v1;
            acc[rf][nf][2] = v2; acc[rf][nf][3] = v3;
            ss0 += v0 * v0; ss1 += v1 * v1; ss2 += v2 * v2; ss3 += v3 * v3;
        }
#pragma unroll
        for (int m = 1; m < 16; m <<= 1) {
            ss0 += __shfl_xor(ss0, m);
            ss1 += __shfl_xor(ss1, m);
            ss2 += __shfl_xor(ss2, m);
            ss3 += __shfl_xor(ss3, m);
        }
        float ssv = (rl == 0) ? ss0 : (rl == 1) ? ss1 : (rl == 2) ? ss2 : ss3;
        if (rl < 4) ssLDS[w][rf * 16 + g * 4 + rl] = ssv;
    }
    __syncthreads();
    if (tid < 32) {
        float t = ssLDS[0][tid] + ssLDS[1][tid] + ssLDS[2][tid] + ssLDS[3][tid];
        invLDS[tid] = (t > 0.f) ? rsqrtf(t) : 1.0f;
    }
    __syncthreads();
#pragma unroll
    for (int rf = 0; rf < 2; ++rf)
#pragma unroll
        for (int j = 0; j < 4; ++j) {
            const int row = rf * 16 + g * 4 + j;
            const float inv = invLDS[row];
#pragma unroll
            for (int nf = 0; nf < 4; ++nf)
                h1b[(size_t)(row0 + row) * D + w * 64 + nf * 16 + rl] =
                    (__bf16)(acc[rf][nf][j] * inv);
        }
}

// ---------------------------------------------------------------------------
// fused_layer1: Out[1024][256] = l2norm(relu(X1 @ W1^T + b1)), X1 row i =
// [h1[i] | mean_j h1[1024+i*10+j]] built on the fly in A-staging (h1 bf16).
// B staged from fp32 W1 with inline cvt + reg prefetch. RB=32.
// ---------------------------------------------------------------------------
__global__ __launch_bounds__(256, 2) void fused_layer1(
        const __bf16* __restrict__ h1, const float* __restrict__ W1,
        const float* __restrict__ b1, float* __restrict__ Out) {
    constexpr int RB = 32;
    __shared__ __bf16 As[RB * 64];
    __shared__ __bf16 Bs[256 * 64];
    __shared__ float ssLDS[4][RB];
    __shared__ float invLDS[RB];

    const int tid = threadIdx.x;
    const int row0 = blockIdx.x * RB;
    const int lane = tid & 63;
    const int w = tid >> 6;
    const int rl = lane & 15;
    const int g = lane >> 4;
    const int rg = tid >> 7, kc8 = (tid >> 4) & 7, lo = tid & 15;
    const int grow = row0 + rg * 16 + lo;

    // B prologue (k0 = 0)
    float4 rb0[8], rb1[8];
#pragma unroll
    for (int s = 0; s < 8; ++s) {
        int i = tid + s * 256;
        int cg = i >> 7, kc = (i >> 4) & 7, blo = i & 15;
        const float* p = W1 + (size_t)(cg * 16 + blo) * K2 + kc * 8;
        rb0[s] = *(const float4*)p;
        rb1[s] = *(const float4*)(p + 4);
    }

    f32x4 acc[2][4];
#pragma unroll
    for (int rf = 0; rf < 2; ++rf)
#pragma unroll
        for (int nf = 0; nf < 4; ++nf) acc[rf][nf] = (f32x4){0.f, 0.f, 0.f, 0.f};

    for (int k0 = 0; k0 < K2; k0 += 64) {
        // fused A-staging (build X1 tile on the fly)
        bf16x8 av;
        if (k0 < 256) {
            av = *(const bf16x8*)(h1 + (size_t)grow * D + k0 + kc8 * 8);
        } else {
            float f[8];
#pragma unroll
            for (int e = 0; e < 8; ++e) f[e] = 0.f;
            const __bf16* base = h1 + (size_t)(BATCH + grow * S1) * D + (k0 - 256) + kc8 * 8;
#pragma unroll
            for (int j = 0; j < S1; ++j) {
                bf16x8 vv = *(const bf16x8*)(base + (size_t)j * D);
#pragma unroll
                for (int e = 0; e < 8; ++e) f[e] += (float)vv[e];
            }
#pragma unroll
            for (int e = 0; e < 8; ++e) av[e] = (__bf16)(f[e] * 0.1f);
        }
        *(bf16x8*)(As + (size_t)tid * 8) = av;
        // B-staging from prefetched regs with cvt
#pragma unroll
        for (int s = 0; s < 8; ++s) {
            int i = tid + s * 256;
            bf16x8 bb;
            bb[0] = (__bf16)rb0[s].x; bb[1] = (__bf16)rb0[s].y;
            bb[2] = (__bf16)rb0[s].z; bb[3] = (__bf16)rb0[s].w;
            bb[4] = (__bf16)rb1[s].x; bb[5] = (__bf16)rb1[s].y;
            bb[6] = (__bf16)rb1[s].z; bb[7] = (__bf16)rb1[s].w;
            *(bf16x8*)(Bs + (size_t)i * 8) = bb;
        }
        __syncthreads();
        if (k0 + 64 < K2) {
#pragma unroll
            for (int s = 0; s < 8; ++s) {
                int i = tid + s * 256;
                int cg = i >> 7, kc = (i >> 4) & 7, blo = i & 15;
                const float* p = W1 + (size_t)(cg * 16 + blo) * K2 + (k0 + 64) + kc * 8;
                rb0[s] = *(const float4*)p;
                rb1[s] = *(const float4*)(p + 4);
            }
        }
#pragma unroll
        for (int kf = 0; kf < 2; ++kf) {
            const int kc = kf * 4 + g;
            bf16x8 af[2], bfr[4];
#pragma unroll
            for (int rf = 0; rf < 2; ++rf)
                af[rf] = *(const bf16x8*)(As + ((size_t)(rf * 8 + kc) * 16 + rl) * 8);
#pragma unroll
            for (int nf = 0; nf < 4; ++nf)
                bfr[nf] = *(const bf16x8*)(Bs + ((size_t)((w * 4 + nf) * 8 + kc) * 16 + rl) * 8);
#pragma unroll
            for (int rf = 0; rf < 2; ++rf)
#pragma unroll
                for (int nf = 0; nf < 4; ++nf)
                    acc[rf][nf] = __builtin_amdgcn_mfma_f32_16x16x32_bf16(
                        af[rf], bfr[nf], acc[rf][nf], 0, 0, 0);
        }
        __syncthreads();
    }

    float bv[4];
#pragma unroll
    for (int nf = 0; nf < 4; ++nf) bv[nf] = b1[w * 64 + nf * 16 + rl];

#pragma unroll
    for (int rf = 0; rf < 2; ++rf) {
        float ss0 = 0.f, ss1 = 0.f, ss2 = 0.f, ss3 = 0.f;
#pragma unroll
        for (int nf = 0; nf < 4; ++nf) {
            float v0 = fmaxf(acc[rf][nf][0] + bv[nf], 0.f);
            float v1 = fmaxf(acc[rf][nf][1] + bv[nf], 0.f);
            float v2 = fmaxf(acc[rf][nf][2] + bv[nf], 0.f);
            float v3 = fmaxf(acc[rf][nf][3] + bv[nf], 0.f);
            acc[rf][nf][0] = v0; acc[rf][nf][1] = v1;
            acc[rf][nf][2] = v2; acc[rf][nf][3] = v3;
            ss0 += v0 * v0; ss1 += v1 * v1; ss2 += v2 * v2; ss3 += v3 * v3;
        }
#pragma unroll
        for (int m = 1; m < 16; m <<= 1) {
            ss0 += __shfl_xor(ss0, m);
            ss1 += __shfl_xor(ss1, m);
            ss2 += __shfl_xor(ss2, m);
            ss3 += __shfl_xor(ss3, m);
        }
        float ssv = (rl == 0) ? ss0 : (rl == 1) ? ss1 : (rl == 2) ? ss2 : ss3;
        if (rl < 4) ssLDS[w][rf * 16 + g * 4 + rl] = ssv;
    }
    __syncthreads();
    if (tid < RB) {
        float t = ssLDS[0][tid] + ssLDS[1][tid] + ssLDS[2][tid] + ssLDS[3][tid];
        invLDS[tid] = (t > 0.f) ? rsqrtf(t) : 1.0f;
    }
    __syncthreads();
#pragma unroll
    for (int rf = 0; rf < 2; ++rf)
#pragma unroll
        for (int j = 0; j < 4; ++j) {
            const int row = rf * 16 + g * 4 + j;
            const float inv = invLDS[row];
#pragma unroll
            for (int nf = 0; nf < 4; ++nf)
                Out[(size_t)(row0 + row) * D + w * 64 + nf * 16 + rl] = acc[rf][nf][j] * inv;
        }
}

// ---------------------------------------------------------------------------
extern "C" void kernel_launch(void* const* d_in, const int* in_sizes, int n_in,
                              void* d_out, int out_size, void* d_ws, size_t ws_size,
                              hipStream_t stream) {
    const float* features = (const float*)d_in[0];
    const float* W0       = (const float*)d_in[1];
    const float* b0       = (const float*)d_in[2];
    const float* W1       = (const float*)d_in[3];
    const float* b1       = (const float*)d_in[4];
    const int*   nodes2   = (const int*)d_in[5];
    const int*   neigh2   = (const int*)d_in[6];
    const int*   neigh1   = (const int*)d_in[7];
    float* out = (float*)d_out;

    __bf16* h1b = (__bf16*)d_ws;   // 11264*256*2 = 5.75 MB

    fused_layer0<<<N1 / 32, 256, 0, stream>>>(features, W0, b0, nodes2, neigh2,
                                              neigh1, h1b);
    fused_layer1<<<BATCH / 32, 256, 0, stream>>>(h1b, W1, b1, out);
}